// Round 1
// baseline (296.340 us; speedup 1.0000x reference)
//
#include <hip/hip_runtime.h>
#include <hip/hip_bf16.h>
#include <stdint.h>

#define S_SZ 4096
// (1/sqrt(256)) * log2(e): scores come out in exp2 domain
#define SCL 0.09016844005586937f

typedef short bf16x8 __attribute__((ext_vector_type(8)));
typedef float f32x4 __attribute__((ext_vector_type(8/2)));
typedef unsigned short u16;

#define MFMA16(a,b,c) __builtin_amdgcn_mfma_f32_16x16x32_bf16(a,b,c,0,0,0)

__device__ __forceinline__ u16 f2bf(float f){
    union { float f; uint32_t u; } v; v.f = f;
    return (u16)((v.u + 0x7FFFu + ((v.u >> 16) & 1u)) >> 16);
}

__device__ __forceinline__ void async16(const void* g, void* l){
    __builtin_amdgcn_global_load_lds(
        (const __attribute__((address_space(1))) unsigned int*)g,
        (__attribute__((address_space(3))) unsigned int*)l, 16, 0, 0);
}

// ---------------- weight transpose + cast: Wt[p][dout][din] = bf16(W[din][dout]) -----------
__global__ void wconv_kernel(const float* __restrict__ Wq, const float* __restrict__ Wk,
                             const float* __restrict__ Wv, u16* __restrict__ Wt){
    int idx = blockIdx.x*256 + threadIdx.x;       // 0..196607
    int p = idx >> 16; int rem = idx & 65535;
    int dout = rem >> 8, din = rem & 255;
    const float* W = (p==0) ? Wq : ((p==1) ? Wk : Wv);
    Wt[idx] = f2bf(W[din*256 + dout]);
}

// ---------------- projection GEMM: Out = bf16((X @ W + b) * scale) --------------------------
// mode 0: row-major [row][256]   mode 1: V grouped-transposed [b][s>>3][256][s&7]
__global__ void proj_kernel(const float* __restrict__ X, const u16* __restrict__ Wt,
                            const float* __restrict__ bias, u16* __restrict__ Out,
                            float scale, int mode){
    int w = threadIdx.x >> 6, lane = threadIdx.x & 63;
    int lr = lane & 15, lg = lane >> 4;
    int r0 = blockIdx.x * 64 + w * 16;            // this wave's 16 rows

    bf16x8 a[8];
    #pragma unroll
    for (int ks = 0; ks < 8; ++ks){
        const float* src = X + (size_t)(r0 + lr)*256 + ks*32 + lg*8;
        float4 f0 = *(const float4*)src;
        float4 f1 = *(const float4*)(src+4);
        bf16x8 t;
        t[0]=f2bf(f0.x); t[1]=f2bf(f0.y); t[2]=f2bf(f0.z); t[3]=f2bf(f0.w);
        t[4]=f2bf(f1.x); t[5]=f2bf(f1.y); t[6]=f2bf(f1.z); t[7]=f2bf(f1.w);
        a[ks]=t;
    }
    #pragma unroll
    for (int dt = 0; dt < 16; ++dt){
        f32x4 acc = {0.f,0.f,0.f,0.f};
        #pragma unroll
        for (int ks = 0; ks < 8; ++ks){
            bf16x8 b = *(const bf16x8*)(Wt + (size_t)(dt*16 + lr)*256 + ks*32 + lg*8);
            acc = MFMA16(a[ks], b, acc);
        }
        float bv = bias[dt*16 + lr];
        if (mode == 0){
            #pragma unroll
            for (int r = 0; r < 4; ++r){
                int row = r0 + lg*4 + r;
                Out[(size_t)row*256 + dt*16 + lr] = f2bf((acc[r] + bv)*scale);
            }
        } else {
            int row = r0 + lg*4;                  // 4 consecutive s rows
            int bb = row >> 12;
            int s  = row & 4095;
            ushort4 pk;
            pk.x = f2bf(acc[0]+bv); pk.y = f2bf(acc[1]+bv);
            pk.z = f2bf(acc[2]+bv); pk.w = f2bf(acc[3]+bv);
            u16* dst = Out + (size_t)bb*1048576 + (size_t)(s>>3)*2048 + (dt*16+lr)*8 + (s&7);
            *(ushort4*)dst = pk;
        }
    }
}

// ---------------- flash attention, kv-split partials ---------------------------------------
// grid 512: split = bid&3 (kv range 1024), b = (bid>>2)&3, qblk = bid>>4 (128 q rows)
// block 256 thr = 4 waves x 32 q rows; Q frags in regs; K/V chunk 64 in LDS
__global__ __launch_bounds__(256, 2)
void attn_kernel(const u16* __restrict__ Qb, const u16* __restrict__ Kb,
                 const u16* __restrict__ Vt, float* __restrict__ Opart,
                 float* __restrict__ Mpart, float* __restrict__ Lpart){
    __shared__ char lds[81920];                   // K 32KB | V 32KB | P 16KB
    char* Klds = lds;
    char* Vlds = lds + 32768;
    char* Plds = lds + 65536;

    int tid = threadIdx.x;
    int w = tid >> 6, lane = tid & 63;
    int lr = lane & 15, lg = lane >> 4;

    int bid = blockIdx.x;
    int split = bid & 3;
    int bb = (bid >> 2) & 3;
    int qb = bid >> 4;
    int qrow0 = qb*128 + w*32;

    const u16* Qbase = Qb + (size_t)bb*S_SZ*256;
    const u16* Kbase = Kb + (size_t)bb*S_SZ*256;
    const u16* Vbase = Vt + (size_t)bb*S_SZ*256;  // grouped layout, same footprint

    bf16x8 qf[2][8];
    #pragma unroll
    for (int qt = 0; qt < 2; ++qt)
      #pragma unroll
      for (int ks = 0; ks < 8; ++ks)
        qf[qt][ks] = *(const bf16x8*)(Qbase + (size_t)(qrow0 + qt*16 + lr)*256 + ks*32 + lg*8);

    f32x4 zero4 = {0.f,0.f,0.f,0.f};
    f32x4 acc[2][16];
    #pragma unroll
    for (int qt=0;qt<2;++qt)
      #pragma unroll
      for (int dt=0;dt<16;++dt) acc[qt][dt] = zero4;
    float m[2][4], l[2][4];
    #pragma unroll
    for (int qt=0;qt<2;++qt)
      #pragma unroll
      for (int r=0;r<4;++r){ m[qt][r] = -1e30f; l[qt][r] = 0.f; }

    int kv0 = split*1024;
    char* Pw = Plds + w*4096;                     // this wave's P tile [32][128B], swizzled

    for (int ch = 0; ch < 16; ++ch){
        int kvbase = kv0 + ch*64;
        // stage K (xor-swizzled source -> linear LDS dest; read applies same XOR)
        #pragma unroll
        for (int i = 0; i < 8; ++i){
            int o = i*4096 + tid*16;
            int r = o >> 9, cb = o & 511;
            const char* src = (const char*)Kbase + (size_t)(kvbase + r)*512 + (cb ^ ((r&7)<<4));
            async16(src, Klds + o);
        }
        // stage V (linear copy; global layout already [s/8][d][8])
        const char* vsrc = (const char*)Vbase + (size_t)kvbase*512;
        #pragma unroll
        for (int i = 0; i < 8; ++i){
            int o = i*4096 + tid*16;
            async16(vsrc + o, Vlds + o);
        }
        __syncthreads();

        // ---- QK^T: sc[qt][kt] = Q(32 rows) x K^T(64 cols), k-depth 256
        f32x4 sc[2][4];
        #pragma unroll
        for (int qt=0;qt<2;++qt)
          #pragma unroll
          for (int kt=0;kt<4;++kt) sc[qt][kt] = zero4;
        #pragma unroll
        for (int ks=0;ks<8;++ks){
            #pragma unroll
            for (int kt=0;kt<4;++kt){
                int krow = kt*16 + lr;
                bf16x8 kf = *(const bf16x8*)(Klds + krow*512 + ((ks*64 + lg*16) ^ ((krow&7)<<4)));
                sc[0][kt] = MFMA16(qf[0][ks], kf, sc[0][kt]);
                sc[1][kt] = MFMA16(qf[1][ks], kf, sc[1][kt]);
            }
        }

        // ---- online softmax (exp2 domain; defer-max THR=8)
        float rmax[2][4];
        int need = 0;
        #pragma unroll
        for (int qt=0;qt<2;++qt){
            #pragma unroll
            for (int r=0;r<4;++r){
                float v = fmaxf(fmaxf(sc[qt][0][r], sc[qt][1][r]), fmaxf(sc[qt][2][r], sc[qt][3][r]));
                v = fmaxf(v, __shfl_xor(v, 1));
                v = fmaxf(v, __shfl_xor(v, 2));
                v = fmaxf(v, __shfl_xor(v, 4));
                v = fmaxf(v, __shfl_xor(v, 8));
                rmax[qt][r] = v;
                need |= (v > m[qt][r] + 8.0f) ? 1 : 0;
            }
        }
        if (__any(need)){
            #pragma unroll
            for (int qt=0;qt<2;++qt){
                #pragma unroll
                for (int r=0;r<4;++r){
                    float mn = fmaxf(m[qt][r], rmax[qt][r]);
                    float alpha = __builtin_amdgcn_exp2f(m[qt][r] - mn);
                    m[qt][r] = mn;
                    l[qt][r] *= alpha;
                    #pragma unroll
                    for (int dt=0;dt<16;++dt) acc[qt][dt][r] *= alpha;
                }
            }
        }
        #pragma unroll
        for (int qt=0;qt<2;++qt){
            #pragma unroll
            for (int r=0;r<4;++r){
                float mm = m[qt][r];
                float rs = 0.f;
                int q = qt*16 + lg*4 + r;
                #pragma unroll
                for (int kt=0;kt<4;++kt){
                    float p = __builtin_amdgcn_exp2f(sc[qt][kt][r] - mm);
                    rs += p;
                    int c = kt*16 + lr;
                    *(u16*)(Pw + q*128 + ((c*2) ^ ((q&7)<<4))) = f2bf(p);
                }
                rs += __shfl_xor(rs, 1);
                rs += __shfl_xor(rs, 2);
                rs += __shfl_xor(rs, 4);
                rs += __shfl_xor(rs, 8);
                l[qt][r] += rs;
            }
        }

        // ---- PV: acc[qt][dt] += P(32 x 64) x V(64 x 256)
        #pragma unroll
        for (int st=0; st<2; ++st){
            bf16x8 pa[2];
            #pragma unroll
            for (int qt=0;qt<2;++qt){
                int q = qt*16 + lr;
                pa[qt] = *(const bf16x8*)(Pw + q*128 + (((st*32 + lg*8)*2) ^ ((q&7)<<4)));
            }
            #pragma unroll
            for (int dt=0;dt<16;++dt){
                bf16x8 vf = *(const bf16x8*)(Vlds + (st*4 + lg)*4096 + (dt*16 + lr)*16);
                acc[0][dt] = MFMA16(pa[0], vf, acc[0][dt]);
                acc[1][dt] = MFMA16(pa[1], vf, acc[1][dt]);
            }
        }
        __syncthreads();   // all waves done with K/V before restage
    }

    // ---- write partials
    size_t pbase = (size_t)(split*4 + bb)*S_SZ*256;
    #pragma unroll
    for (int qt=0;qt<2;++qt){
        #pragma unroll
        for (int dt=0;dt<16;++dt){
            #pragma unroll
            for (int r=0;r<4;++r){
                int row = qrow0 + qt*16 + lg*4 + r;
                Opart[pbase + (size_t)row*256 + dt*16 + lr] = acc[qt][dt][r];
            }
        }
    }
    if (lr == 0){
        #pragma unroll
        for (int qt=0;qt<2;++qt){
            #pragma unroll
            for (int r=0;r<4;++r){
                int row = qrow0 + qt*16 + lg*4 + r;
                Mpart[(split*4+bb)*S_SZ + row] = m[qt][r];
                Lpart[(split*4+bb)*S_SZ + row] = l[qt][r];
            }
        }
    }
}

// ---------------- combine kv-split partials -------------------------------------------------
__global__ void combine_kernel(const float* __restrict__ Opart, const float* __restrict__ Mpart,
                               const float* __restrict__ Lpart, float* __restrict__ out){
    int idx = blockIdx.x*256 + threadIdx.x;       // one float4 per thread
    int d4 = (idx & 63)*4;
    int row = idx >> 6;                            // b*4096 + s
    int bb = row >> 12, srow = row & 4095;
    float m[4], lv[4];
    #pragma unroll
    for (int i=0;i<4;++i){
        m[i]  = Mpart[(i*4+bb)*S_SZ + srow];
        lv[i] = Lpart[(i*4+bb)*S_SZ + srow];
    }
    float M = fmaxf(fmaxf(m[0],m[1]), fmaxf(m[2],m[3]));
    float L = 0.f; float wt[4];
    #pragma unroll
    for (int i=0;i<4;++i){ wt[i] = __builtin_amdgcn_exp2f(m[i]-M); L += lv[i]*wt[i]; }
    float inv = 1.f/L;
    float ox=0.f, oy=0.f, oz=0.f, ow=0.f;
    #pragma unroll
    for (int i=0;i<4;++i){
        float4 oi = *(const float4*)(Opart + (size_t)(i*4+bb)*S_SZ*256 + (size_t)srow*256 + d4);
        ox += oi.x*wt[i]; oy += oi.y*wt[i]; oz += oi.z*wt[i]; ow += oi.w*wt[i];
    }
    float4 o; o.x = ox*inv; o.y = oy*inv; o.z = oz*inv; o.w = ow*inv;
    *(float4*)(out + (size_t)row*256 + d4) = o;
}

extern "C" void kernel_launch(void* const* d_in, const int* in_sizes, int n_in,
                              void* d_out, int out_size, void* d_ws, size_t ws_size,
                              hipStream_t stream) {
    const float* q_in = (const float*)d_in[0];
    const float* k_in = (const float*)d_in[1];
    const float* v_in = (const float*)d_in[2];
    const float* Wq   = (const float*)d_in[3];
    const float* bq   = (const float*)d_in[4];
    const float* Wk   = (const float*)d_in[5];
    const float* bk   = (const float*)d_in[6];
    const float* Wv   = (const float*)d_in[7];
    const float* bv   = (const float*)d_in[8];

    char* ws = (char*)d_ws;
    u16*  Qb    = (u16*)ws;                         // 8,388,608 B
    u16*  Kb    = (u16*)(ws + 8388608);             // 8,388,608 B
    u16*  Vt    = (u16*)(ws + 16777216);            // 8,388,608 B
    u16*  Wt    = (u16*)(ws + 25165824);            // 393,216 B
    float* Opart = (float*)(ws + 33554432);         // 67,108,864 B
    float* Mpart = (float*)(ws + 100663296);        // 262,144 B
    float* Lpart = (float*)(ws + 100925440);        // 262,144 B
    float* out   = (float*)d_out;

    hipLaunchKernelGGL(wconv_kernel,   dim3(768),  dim3(256), 0, stream, Wq, Wk, Wv, Wt);
    hipLaunchKernelGGL(proj_kernel,    dim3(256),  dim3(256), 0, stream, q_in, Wt,        bq, Qb, SCL, 0);
    hipLaunchKernelGGL(proj_kernel,    dim3(256),  dim3(256), 0, stream, k_in, Wt+65536,  bk, Kb, 1.f, 0);
    hipLaunchKernelGGL(proj_kernel,    dim3(256),  dim3(256), 0, stream, v_in, Wt+131072, bv, Vt, 1.f, 1);
    hipLaunchKernelGGL(attn_kernel,    dim3(512),  dim3(256), 0, stream, Qb, Kb, Vt, Opart, Mpart, Lpart);
    hipLaunchKernelGGL(combine_kernel, dim3(4096), dim3(256), 0, stream, Opart, Mpart, Lpart, out);
}

// Round 4
// 243.324 us; speedup vs baseline: 1.2179x; 1.2179x over previous
//
#include <hip/hip_runtime.h>
#include <hip/hip_bf16.h>
#include <stdint.h>

#define S_SZ 4096
// (1/sqrt(256)) * log2(e): scores come out in exp2 domain
#define SCL 0.09016844005586937f

typedef short bf16x8 __attribute__((ext_vector_type(8)));
typedef float f32x4 __attribute__((ext_vector_type(4)));
typedef unsigned short u16;

#define MFMA16(a,b,c) __builtin_amdgcn_mfma_f32_16x16x32_bf16(a,b,c,0,0,0)

__device__ __forceinline__ u16 f2bf(float f){
    union { float f; uint32_t u; } v; v.f = f;
    return (u16)((v.u + 0x7FFFu + ((v.u >> 16) & 1u)) >> 16);
}

__device__ __forceinline__ void async16(const void* g, void* l){
    __builtin_amdgcn_global_load_lds(
        (const __attribute__((address_space(1))) unsigned int*)g,
        (__attribute__((address_space(3))) unsigned int*)l, 16, 0, 0);
}

// ---------------- weight transpose + cast: Wt[p][dout][din] = bf16(W[din][dout]) -----------
__global__ void wconv_kernel(const float* __restrict__ Wq, const float* __restrict__ Wk,
                             const float* __restrict__ Wv, u16* __restrict__ Wt){
    int idx = blockIdx.x*256 + threadIdx.x;       // 0..196607
    int p = idx >> 16; int rem = idx & 65535;
    int dout = rem >> 8, din = rem & 255;
    const float* W = (p==0) ? Wq : ((p==1) ? Wk : Wv);
    Wt[idx] = f2bf(W[din*256 + dout]);
}

// ---------------- projection GEMM: Out = bf16((X @ W + b) * scale) --------------------------
// mode 0: row-major [row][256]   mode 1: V grouped-transposed [b][s>>3][256][s&7]
__global__ void proj_kernel(const float* __restrict__ X, const u16* __restrict__ Wt,
                            const float* __restrict__ bias, u16* __restrict__ Out,
                            float scale, int mode){
    int w = threadIdx.x >> 6, lane = threadIdx.x & 63;
    int lr = lane & 15, lg = lane >> 4;
    int r0 = blockIdx.x * 64 + w * 16;            // this wave's 16 rows

    bf16x8 a[8];
    #pragma unroll
    for (int ks = 0; ks < 8; ++ks){
        const float* src = X + (size_t)(r0 + lr)*256 + ks*32 + lg*8;
        float4 f0 = *(const float4*)src;
        float4 f1 = *(const float4*)(src+4);
        bf16x8 t;
        t[0]=f2bf(f0.x); t[1]=f2bf(f0.y); t[2]=f2bf(f0.z); t[3]=f2bf(f0.w);
        t[4]=f2bf(f1.x); t[5]=f2bf(f1.y); t[6]=f2bf(f1.z); t[7]=f2bf(f1.w);
        a[ks]=t;
    }
    #pragma unroll
    for (int dt = 0; dt < 16; ++dt){
        f32x4 acc = {0.f,0.f,0.f,0.f};
        #pragma unroll
        for (int ks = 0; ks < 8; ++ks){
            bf16x8 b = *(const bf16x8*)(Wt + (size_t)(dt*16 + lr)*256 + ks*32 + lg*8);
            acc = MFMA16(a[ks], b, acc);
        }
        float bv = bias[dt*16 + lr];
        if (mode == 0){
            #pragma unroll
            for (int r = 0; r < 4; ++r){
                int row = r0 + lg*4 + r;
                Out[(size_t)row*256 + dt*16 + lr] = f2bf((acc[r] + bv)*scale);
            }
        } else {
            int row = r0 + lg*4;                  // 4 consecutive s rows
            int bb = row >> 12;
            int s  = row & 4095;
            ushort4 pk;
            pk.x = f2bf(acc[0]+bv); pk.y = f2bf(acc[1]+bv);
            pk.z = f2bf(acc[2]+bv); pk.w = f2bf(acc[3]+bv);
            u16* dst = Out + (size_t)bb*1048576 + (size_t)(s>>3)*2048 + (dt*16+lr)*8 + (s&7);
            *(ushort4*)dst = pk;
        }
    }
}

// ---------------- flash attention, kv-split partials ---------------------------------------
// grid 512, XCD-aware: xcd=bid&7 hosts 2 (bb,split) combos x 32 q-blocks
// block 256 thr = 4 waves x 32 q rows; Q frags in regs; K/V chunk 32, double-buffered LDS
#define CH_ROWS 32
#define NCH     32          /* 1024 kv rows per split / 32 */
#define P_STRIDE 72

__global__ __launch_bounds__(256, 2)
void attn_kernel(const u16* __restrict__ Qb, const u16* __restrict__ Kb,
                 const u16* __restrict__ Vt, float* __restrict__ Opart,
                 float* __restrict__ Mpart, float* __restrict__ Lpart){
    __shared__ char lds[75776];                   // K dbuf 32KB | V dbuf 32KB | P 10KB
    // layout: K0 @0, K1 @16384, V0 @32768, V1 @49152, P @65536
    char* Plds = lds + 65536;

    int tid = threadIdx.x;
    int w = tid >> 6, lane = tid & 63;
    int lr = lane & 15, lg = lane >> 4;

    // XCD-aware decode: same (bb,split) combo stays on one XCD for L2 reuse
    int bid = blockIdx.x;
    int xcd = bid & 7;
    int loc = bid >> 3;                 // 0..63
    int combo = xcd*2 + (loc >> 5);     // 0..15
    int qb = loc & 31;
    int bb = combo >> 2;
    int split = combo & 3;
    int qrow0 = qb*128 + w*32;

    const u16* Qbase = Qb + (size_t)bb*S_SZ*256;
    const u16* Kbase = Kb + (size_t)bb*S_SZ*256;
    const u16* Vbase = Vt + (size_t)bb*S_SZ*256;  // grouped layout, same footprint

    bf16x8 qf[2][8];
    #pragma unroll
    for (int qt = 0; qt < 2; ++qt)
      #pragma unroll
      for (int ks = 0; ks < 8; ++ks)
        qf[qt][ks] = *(const bf16x8*)(Qbase + (size_t)(qrow0 + qt*16 + lr)*256 + ks*32 + lg*8);

    f32x4 zero4 = {0.f,0.f,0.f,0.f};
    f32x4 acc[2][16];
    #pragma unroll
    for (int qt=0;qt<2;++qt)
      #pragma unroll
      for (int dt=0;dt<16;++dt) acc[qt][dt] = zero4;
    float m[2][4], l[2][4];
    #pragma unroll
    for (int qt=0;qt<2;++qt)
      #pragma unroll
      for (int r=0;r<4;++r){ m[qt][r] = -1e30f; l[qt][r] = 0.f; }

    int kv0 = split*1024;
    char* Pw = Plds + w*2560;                     // [32 rows][stride 72B]

    // ---- prologue: stage chunk 0 into buf 0
    {
        #pragma unroll
        for (int i = 0; i < 4; ++i){
            int o = i*4096 + tid*16;
            int r = o >> 9, cb = o & 511;
            async16((const char*)Kbase + (size_t)(kv0 + r)*512 + (cb ^ ((r&7)<<4)), lds + o);
        }
        const char* vsrc = (const char*)Vbase + (size_t)kv0*512;
        #pragma unroll
        for (int i = 0; i < 4; ++i){
            int o = i*4096 + tid*16;
            async16(vsrc + o, lds + 32768 + o);
        }
    }
    __syncthreads();

    int buf = 0;
    for (int ch = 0; ch < NCH; ++ch){
        // ---- prefetch next chunk into buf^1 (overlaps with compute below)
        if (ch < NCH-1){
            int kvn = kv0 + (ch+1)*CH_ROWS;
            char* Kn = lds + (buf^1)*16384;
            char* Vn = lds + 32768 + (buf^1)*16384;
            #pragma unroll
            for (int i = 0; i < 4; ++i){
                int o = i*4096 + tid*16;
                int r = o >> 9, cb = o & 511;
                async16((const char*)Kbase + (size_t)(kvn + r)*512 + (cb ^ ((r&7)<<4)), Kn + o);
            }
            const char* vsrc = (const char*)Vbase + (size_t)kvn*512;
            #pragma unroll
            for (int i = 0; i < 4; ++i){
                int o = i*4096 + tid*16;
                async16(vsrc + o, Vn + o);
            }
        }
        char* Kl = lds + buf*16384;
        char* Vl = lds + 32768 + buf*16384;

        // ---- QK^T: sc[qt][kt] = Q(32 rows) x K^T(32 cols), k-depth 256
        f32x4 sc[2][2];
        #pragma unroll
        for (int qt=0;qt<2;++qt){ sc[qt][0] = zero4; sc[qt][1] = zero4; }
        __builtin_amdgcn_s_setprio(1);
        #pragma unroll
        for (int ks=0;ks<8;++ks){
            #pragma unroll
            for (int kt=0;kt<2;++kt){
                int krow = kt*16 + lr;
                bf16x8 kf = *(const bf16x8*)(Kl + krow*512 + ((ks*64 + lg*16) ^ ((krow&7)<<4)));
                sc[0][kt] = MFMA16(qf[0][ks], kf, sc[0][kt]);
                sc[1][kt] = MFMA16(qf[1][ks], kf, sc[1][kt]);
            }
        }
        __builtin_amdgcn_s_setprio(0);

        // ---- online softmax (exp2 domain; defer-max THR=8)
        float rmax[2][4];
        int need = 0;
        #pragma unroll
        for (int qt=0;qt<2;++qt){
            #pragma unroll
            for (int r=0;r<4;++r){
                float v = fmaxf(sc[qt][0][r], sc[qt][1][r]);
                v = fmaxf(v, __shfl_xor(v, 1));
                v = fmaxf(v, __shfl_xor(v, 2));
                v = fmaxf(v, __shfl_xor(v, 4));
                v = fmaxf(v, __shfl_xor(v, 8));
                rmax[qt][r] = v;
                need |= (v > m[qt][r] + 8.0f) ? 1 : 0;
            }
        }
        if (__any(need)){
            #pragma unroll
            for (int qt=0;qt<2;++qt){
                #pragma unroll
                for (int r=0;r<4;++r){
                    float mn = fmaxf(m[qt][r], rmax[qt][r]);
                    float alpha = __builtin_amdgcn_exp2f(m[qt][r] - mn);
                    m[qt][r] = mn;
                    l[qt][r] *= alpha;
                    #pragma unroll
                    for (int dt=0;dt<16;++dt) acc[qt][dt][r] *= alpha;
                }
            }
        }
        #pragma unroll
        for (int qt=0;qt<2;++qt){
            #pragma unroll
            for (int r=0;r<4;++r){
                float mm = m[qt][r];
                float rs = 0.f;
                int q = qt*16 + lg*4 + r;
                #pragma unroll
                for (int kt=0;kt<2;++kt){
                    float p = __builtin_amdgcn_exp2f(sc[qt][kt][r] - mm);
                    rs += p;
                    int c = kt*16 + lr;
                    *(u16*)(Pw + q*P_STRIDE + c*2) = f2bf(p);
                }
                rs += __shfl_xor(rs, 1);
                rs += __shfl_xor(rs, 2);
                rs += __shfl_xor(rs, 4);
                rs += __shfl_xor(rs, 8);
                l[qt][r] += rs;
            }
        }

        // ---- PV: acc[qt][dt] += P(32 x 32) x V(32 x 256)
        bf16x8 pa[2];
        #pragma unroll
        for (int qt=0;qt<2;++qt)
            pa[qt] = *(const bf16x8*)(Pw + (qt*16 + lr)*P_STRIDE + lg*16);
        __builtin_amdgcn_s_setprio(1);
        #pragma unroll
        for (int dt=0;dt<16;++dt){
            bf16x8 vf = *(const bf16x8*)(Vl + lg*4096 + (dt*16 + lr)*16);
            acc[0][dt] = MFMA16(pa[0], vf, acc[0][dt]);
            acc[1][dt] = MFMA16(pa[1], vf, acc[1][dt]);
        }
        __builtin_amdgcn_s_setprio(0);

        __syncthreads();   // drains prefetch vmcnt + all waves done with buf before overwrite
        buf ^= 1;
    }

    // ---- write partials
    size_t pbase = (size_t)(split*4 + bb)*S_SZ*256;
    #pragma unroll
    for (int qt=0;qt<2;++qt){
        #pragma unroll
        for (int dt=0;dt<16;++dt){
            #pragma unroll
            for (int r=0;r<4;++r){
                int row = qrow0 + qt*16 + lg*4 + r;
                Opart[pbase + (size_t)row*256 + dt*16 + lr] = acc[qt][dt][r];
            }
        }
    }
    if (lr == 0){
        #pragma unroll
        for (int qt=0;qt<2;++qt){
            #pragma unroll
            for (int r=0;r<4;++r){
                int row = qrow0 + qt*16 + lg*4 + r;
                Mpart[(split*4+bb)*S_SZ + row] = m[qt][r];
                Lpart[(split*4+bb)*S_SZ + row] = l[qt][r];
            }
        }
    }
}

// ---------------- combine kv-split partials -------------------------------------------------
__global__ void combine_kernel(const float* __restrict__ Opart, const float* __restrict__ Mpart,
                               const float* __restrict__ Lpart, float* __restrict__ out){
    int idx = blockIdx.x*256 + threadIdx.x;       // one float4 per thread
    int d4 = (idx & 63)*4;
    int row = idx >> 6;                            // b*4096 + s
    int bb = row >> 12, srow = row & 4095;
    float m[4], lv[4];
    #pragma unroll
    for (int i=0;i<4;++i){
        m[i]  = Mpart[(i*4+bb)*S_SZ + srow];
        lv[i] = Lpart[(i*4+bb)*S_SZ + srow];
    }
    float M = fmaxf(fmaxf(m[0],m[1]), fmaxf(m[2],m[3]));
    float L = 0.f; float wt[4];
    #pragma unroll
    for (int i=0;i<4;++i){ wt[i] = __builtin_amdgcn_exp2f(m[i]-M); L += lv[i]*wt[i]; }
    float inv = 1.f/L;
    float ox=0.f, oy=0.f, oz=0.f, ow=0.f;
    #pragma unroll
    for (int i=0;i<4;++i){
        float4 oi = *(const float4*)(Opart + (size_t)(i*4+bb)*S_SZ*256 + (size_t)srow*256 + d4);
        ox += oi.x*wt[i]; oy += oi.y*wt[i]; oz += oi.z*wt[i]; ow += oi.w*wt[i];
    }
    float4 o; o.x = ox*inv; o.y = oy*inv; o.z = oz*inv; o.w = ow*inv;
    *(float4*)(out + (size_t)row*256 + d4) = o;
}

extern "C" void kernel_launch(void* const* d_in, const int* in_sizes, int n_in,
                              void* d_out, int out_size, void* d_ws, size_t ws_size,
                              hipStream_t stream) {
    const float* q_in = (const float*)d_in[0];
    const float* k_in = (const float*)d_in[1];
    const float* v_in = (const float*)d_in[2];
    const float* Wq   = (const float*)d_in[3];
    const float* bq   = (const float*)d_in[4];
    const float* Wk   = (const float*)d_in[5];
    const float* bk   = (const float*)d_in[6];
    const float* Wv   = (const float*)d_in[7];
    const float* bv   = (const float*)d_in[8];

    char* ws = (char*)d_ws;
    u16*  Qb    = (u16*)ws;                         // 8,388,608 B
    u16*  Kb    = (u16*)(ws + 8388608);             // 8,388,608 B
    u16*  Vt    = (u16*)(ws + 16777216);            // 8,388,608 B
    u16*  Wt    = (u16*)(ws + 25165824);            // 393,216 B
    float* Opart = (float*)(ws + 33554432);         // 67,108,864 B
    float* Mpart = (float*)(ws + 100663296);        // 262,144 B
    float* Lpart = (float*)(ws + 100925440);        // 262,144 B
    float* out   = (float*)d_out;

    hipLaunchKernelGGL(wconv_kernel,   dim3(768),  dim3(256), 0, stream, Wq, Wk, Wv, Wt);
    hipLaunchKernelGGL(proj_kernel,    dim3(256),  dim3(256), 0, stream, q_in, Wt,        bq, Qb, SCL, 0);
    hipLaunchKernelGGL(proj_kernel,    dim3(256),  dim3(256), 0, stream, k_in, Wt+65536,  bk, Kb, 1.f, 0);
    hipLaunchKernelGGL(proj_kernel,    dim3(256),  dim3(256), 0, stream, v_in, Wt+131072, bv, Vt, 1.f, 1);
    hipLaunchKernelGGL(attn_kernel,    dim3(512),  dim3(256), 0, stream, Qb, Kb, Vt, Opart, Mpart, Lpart);
    hipLaunchKernelGGL(combine_kernel, dim3(4096), dim3(256), 0, stream, Opart, Mpart, Lpart, out);
}